// Round 25
// baseline (448.312 us; speedup 1.0000x reference)
//
#include <hip/hip_runtime.h>
#include <stdint.h>
#include <stddef.h>

#define NN 150000   // nodes
#define NPAD 150016 // padded rows (= 586 * 256)
#define NE 300000   // edges
#define NG 256      // graphs
#define DE 128      // embedding dim
#define DH 256      // hidden dim

typedef unsigned short bf16_t;
typedef __attribute__((ext_vector_type(8))) short bf16x8;
typedef __attribute__((ext_vector_type(4))) float f32x4;

__device__ __forceinline__ float bf2f(unsigned int u) {
    union { unsigned int i; float f; } v; v.i = u << 16; return v.f;
}
__device__ __forceinline__ bf16_t f2bf(float f) {
    union { float f; unsigned int i; } v; v.f = f;
    unsigned int x = v.i;
    return (bf16_t)((x + 0x7fffu + ((x >> 16) & 1u)) >> 16);   // RNE
}

// ---------------------------------------------------------------- utility

__global__ void k_zero(int* __restrict__ p, int n) {
    int i = blockIdx.x * blockDim.x + threadIdx.x;
    if (i < n) p[i] = 0;
}

// ---------------------------------------------------------------- precompute

__global__ void k_hist(const int* __restrict__ dst, int* __restrict__ cnt) {
    int e = blockIdx.x * blockDim.x + threadIdx.x;
    if (e < NE) atomicAdd(&cnt[dst[e]], 1);
}

#define SCAN_CHUNK 1024
// block sums for rowptr scan; ALSO computes dinv (padded: [NN,NPAD) -> 0)
__global__ void k_scan1(const int* __restrict__ cnt, int* __restrict__ bsum,
                        float* __restrict__ dinv) {
    __shared__ int sd[256];
    int base = blockIdx.x * SCAN_CHUNK;
    int t = threadIdx.x;
    int s = 0;
#pragma unroll
    for (int j = 0; j < 4; j++) {
        int i = base + t * 4 + j;
        if (i < NN) s += cnt[i];
        if (i < NPAD) dinv[i] = (i < NN) ? rsqrtf((float)(cnt[i] + 1)) : 0.f;
    }
    sd[t] = s; __syncthreads();
    for (int off = 128; off > 0; off >>= 1) {
        if (t < off) sd[t] += sd[t + off];
        __syncthreads();
    }
    if (t == 0) bsum[blockIdx.x] = sd[0];
}

// parallel exclusive scan over block sums (nb <= 256)
__global__ void k_scan2(int* __restrict__ bsum, int nb) {
    __shared__ int sd[256];
    int t = threadIdx.x;
    int v = (t < nb) ? bsum[t] : 0;
    sd[t] = v; __syncthreads();
    for (int off = 1; off < 256; off <<= 1) {
        int x = (t >= off) ? sd[t - off] : 0;
        __syncthreads();
        sd[t] += x;
        __syncthreads();
    }
    if (t < nb) bsum[t] = sd[t] - v;   // exclusive prefix
}

// also zeroes cnt after reading (fill-cursor prep for k_scatter)
__global__ void k_scan3(int* __restrict__ cnt, const int* __restrict__ bsum,
                        int* __restrict__ rowptr) {
    __shared__ int sd[256];
    int base = blockIdx.x * SCAN_CHUNK;
    int t = threadIdx.x;
    int v[4]; int s = 0;
#pragma unroll
    for (int j = 0; j < 4; j++) {
        int i = base + t * 4 + j;
        v[j] = (i < NN) ? cnt[i] : 0;
        s += v[j];
    }
    sd[t] = s; __syncthreads();
    for (int off = 1; off < 256; off <<= 1) {
        int x = (t >= off) ? sd[t - off] : 0;
        __syncthreads();
        sd[t] += x;
        __syncthreads();
    }
    int pre = bsum[blockIdx.x] + ((t == 0) ? 0 : sd[t - 1]);
#pragma unroll
    for (int j = 0; j < 4; j++) {
        int i = base + t * 4 + j;
        if (i < NN) { rowptr[i] = pre; pre += v[j]; cnt[i] = 0; }
    }
    if (blockIdx.x == 0 && t == 0) rowptr[NN] = NE;
}

// CSR scatter; ALSO computes gstart (independent work, same grid covers NN)
__global__ void k_scatter(const int* __restrict__ src, const int* __restrict__ dst,
                          const int* __restrict__ rowptr, int* __restrict__ fill,
                          int* __restrict__ col, const int* __restrict__ batch,
                          int* __restrict__ gstart) {
    int e = blockIdx.x * blockDim.x + threadIdx.x;
    if (e < NE) {
        int d = dst[e];
        int p = rowptr[d] + atomicAdd(&fill[d], 1);
        col[p] = src[e];
    }
    if (e < NN) {
        int g = batch[e];
        int gp = (e == 0) ? -1 : batch[e - 1];
        for (int gg = gp + 1; gg <= g; ++gg) gstart[gg] = e;
        if (e == NN - 1) {
            for (int gg = g + 1; gg <= NG; ++gg) gstart[gg] = NN;
        }
    }
}

// ------------------------------------------------------- weight fragment prep
// all 4 layers in one launch; layer = blockIdx.y, KS = layer? 8 : 4.
// element (q,l,j) = W[ks*32 + (l>>4)*8 + j][nt*16 + (l&15)], q = nt*KS+ks

__global__ void k_wprep4(const float* __restrict__ W0, const float* __restrict__ W1,
                         const float* __restrict__ W2, const float* __restrict__ W3,
                         bf16_t* __restrict__ h0, bf16_t* __restrict__ h1,
                         bf16_t* __restrict__ h2, bf16_t* __restrict__ h3) {
    int layer = blockIdx.y;
    int KS = (layer == 0) ? 4 : 8;
    const float* W = (layer == 0) ? W0 : (layer == 1) ? W1 : (layer == 2) ? W2 : W3;
    bf16_t* whi = (layer == 0) ? h0 : (layer == 1) ? h1 : (layer == 2) ? h2 : h3;
    int tid = blockIdx.x * blockDim.x + threadIdx.x;
    int total = 16 * KS * 64;
    if (tid >= total) return;
    int l = tid & 63, q = tid >> 6;
    int ks = q % KS;
    int nt = q / KS;
    int row0 = ks * 32 + (l >> 4) * 8;
    int colc = nt * 16 + (l & 15);
    unsigned hi[8];
#pragma unroll
    for (int j = 0; j < 8; j++)
        hi[j] = f2bf(W[(size_t)(row0 + j) * DH + colc]);
    uint4 ph;
    ph.x = hi[0] | (hi[1] << 16); ph.y = hi[2] | (hi[3] << 16);
    ph.z = hi[4] | (hi[5] << 16); ph.w = hi[6] | (hi[7] << 16);
    ((uint4*)whi)[q * 64 + l] = ph;
}

__device__ __forceinline__ void unpack8(uint4 u, float* f) {
    f[0] = bf2f(u.x & 0xffffu); f[1] = bf2f(u.x >> 16);
    f[2] = bf2f(u.y & 0xffffu); f[3] = bf2f(u.y >> 16);
    f[4] = bf2f(u.z & 0xffffu); f[5] = bf2f(u.z >> 16);
    f[6] = bf2f(u.w & 0xffffu); f[7] = bf2f(u.w >> 16);
}
__device__ __forceinline__ uint4 pack8(const float* f, float sc) {
    uint4 o;
    o.x = (unsigned)f2bf(sc * f[0]) | ((unsigned)f2bf(sc * f[1]) << 16);
    o.y = (unsigned)f2bf(sc * f[2]) | ((unsigned)f2bf(sc * f[3]) << 16);
    o.z = (unsigned)f2bf(sc * f[4]) | ((unsigned)f2bf(sc * f[5]) << 16);
    o.w = (unsigned)f2bf(sc * f[6]) | ((unsigned)f2bf(sc * f[7]) << 16);
    return o;
}

// ------------------------------------------- fused embed + layer-0 aggregation
// y[i] = dinv[i]*( dinv[i]*emb[nids[i]] + sum_nb dinv[s]*emb[nids[s]] ), bf16.
// thread = (node, 16-elem chunk): 8 threads/node, 32B per gather step.

__global__ void k_agg_emb(const int* __restrict__ nids, const float* __restrict__ emb,
                          const float* __restrict__ dinv, const int* __restrict__ rowptr,
                          const int* __restrict__ col, bf16_t* __restrict__ y) {
    int idx = blockIdx.x * 256 + threadIdx.x;
    if (idx >= NN * 8) return;
    int node = idx >> 3;
    int c = idx & 7;
    size_t off = (size_t)c * 16;
    float di = dinv[node];
    float acc[16];
    {
        const float4* sp = (const float4*)(emb + (size_t)nids[node] * DE + off);
        float4 u0 = sp[0], u1 = sp[1], u2 = sp[2], u3 = sp[3];
        acc[0] = di * u0.x;  acc[1] = di * u0.y;  acc[2] = di * u0.z;  acc[3] = di * u0.w;
        acc[4] = di * u1.x;  acc[5] = di * u1.y;  acc[6] = di * u1.z;  acc[7] = di * u1.w;
        acc[8] = di * u2.x;  acc[9] = di * u2.y;  acc[10] = di * u2.z; acc[11] = di * u2.w;
        acc[12] = di * u3.x; acc[13] = di * u3.y; acc[14] = di * u3.z; acc[15] = di * u3.w;
    }
    int r0 = rowptr[node], r1 = rowptr[node + 1];
    for (int r = r0; r < r1; ++r) {
        int s = col[r];
        float ds = dinv[s];
        const float4* np = (const float4*)(emb + (size_t)nids[s] * DE + off);
        float4 n0 = np[0], n1 = np[1], n2 = np[2], n3 = np[3];
        acc[0] = fmaf(ds, n0.x, acc[0]);   acc[1] = fmaf(ds, n0.y, acc[1]);
        acc[2] = fmaf(ds, n0.z, acc[2]);   acc[3] = fmaf(ds, n0.w, acc[3]);
        acc[4] = fmaf(ds, n1.x, acc[4]);   acc[5] = fmaf(ds, n1.y, acc[5]);
        acc[6] = fmaf(ds, n1.z, acc[6]);   acc[7] = fmaf(ds, n1.w, acc[7]);
        acc[8] = fmaf(ds, n2.x, acc[8]);   acc[9] = fmaf(ds, n2.y, acc[9]);
        acc[10] = fmaf(ds, n2.z, acc[10]); acc[11] = fmaf(ds, n2.w, acc[11]);
        acc[12] = fmaf(ds, n3.x, acc[12]); acc[13] = fmaf(ds, n3.y, acc[13]);
        acc[14] = fmaf(ds, n3.z, acc[14]); acc[15] = fmaf(ds, n3.w, acc[15]);
    }
    uint4* yp = (uint4*)(y + (size_t)node * DE + off);
    yp[0] = pack8(acc, di);
    yp[1] = pack8(acc + 8, di);
}

// ------------------------------------------------------------- aggregation
// x holds z = dinv*h (pre-scaled). y[i] = dinv[i] * ( z[i] + sum_nb z[s] ).
// thread = (node, 16-elem chunk): two independent uint4 gathers per neighbor.

template <int W>
__global__ void k_agg(const bf16_t* __restrict__ x, const float* __restrict__ dinv,
                      const int* __restrict__ rowptr, const int* __restrict__ col,
                      bf16_t* __restrict__ y) {
    constexpr int CH = W / 16;                 // chunks per node
    constexpr int SH = (W == 128) ? 3 : 4;
    int idx = blockIdx.x * 256 + threadIdx.x;
    if (idx >= NN * CH) return;
    int node = idx >> SH;
    int c = idx & (CH - 1);
    size_t off = (size_t)c * 16;
    float di = dinv[node];
    float acc[16];
    {
        const uint4* xp = (const uint4*)(x + (size_t)node * W + off);
        uint4 u0 = xp[0], u1 = xp[1];
        unpack8(u0, acc);
        unpack8(u1, acc + 8);
    }
    int r0 = rowptr[node], r1 = rowptr[node + 1];
    for (int r = r0; r < r1; ++r) {
        int s = col[r];
        const uint4* np = (const uint4*)(x + (size_t)s * W + off);
        uint4 v0 = np[0], v1 = np[1];
        float f[16];
        unpack8(v0, f);
        unpack8(v1, f + 8);
#pragma unroll
        for (int j = 0; j < 16; j++) acc[j] += f[j];
    }
    uint4* yp = (uint4*)(y + (size_t)node * W + off);
    yp[0] = pack8(acc, di);
    yp[1] = pack8(acc + 8, di);
}

// ------------------------------------------------------------------- GEMM
// C[NPAD x 256] = relu(A[NPAD x K] @ W[K x 256] + bias)  [then *dinv if SCALE]
// ZERO-LDS variant: W_hi read directly from L1/L2 (every wave in every
// resident block reads the SAME 8KB nt-slice at the same phase -> L1 serves
// after first touch; weights globally shared across all 1172 blocks). LDS=0
// removes the 64KB cap that pinned occupancy at 2 blocks/CU (~30%) across
// rounds 12-24, and deletes the only barrier. VGPR ~60 -> up to 8 waves/SIMD.
// Differs from failed rounds 5 (1x reuse, hi+lo) and 13 (LDS kept, no
// occupancy gain). Swapped-operand MFMA + paired-nt sector stores kept.

template <int KS, bool SCALE>
__global__ __launch_bounds__(512, 4) void k_gemm_mfma(
    const bf16_t* __restrict__ A, const bf16_t* __restrict__ whi,
    const float* __restrict__ bias, const float* __restrict__ dinv,
    bf16_t* __restrict__ C)
{
    constexpr int K = KS * 32;
    const int t = threadIdx.x;
    const int lane = t & 63;
    const int wave = t >> 6;                      // 0..7
    const int nh = blockIdx.x & 1;
    const int br0 = (blockIdx.x >> 1) * 256;

    // A fragments: wave's 32 rows (2 subtiles of 16), full K.
    const int r0 = br0 + wave * 32;
    bf16x8 a[2][KS];
#pragma unroll
    for (int s = 0; s < 2; s++) {
        const bf16_t* ap = A + (size_t)(r0 + s * 16 + (lane & 15)) * K + (lane >> 4) * 8;
#pragma unroll
        for (int ks = 0; ks < KS; ks++)
            a[s][ks] = *(const bf16x8*)(ap + ks * 32);
    }

    const bf16_t* wbase = whi + ((size_t)nh * 8) * KS * 512 + lane * 8;
    const int rsub = lane & 15;                   // output row within subtile
    const int cq = (lane >> 4) * 4;               // col base within nt tile
    const bool lowhalf = ((lane >> 4) & 1) == 0;  // partner = lane ^ 16
    const size_t row0 = (size_t)(r0 + rsub) * DH;
    const size_t row1 = (size_t)(r0 + 16 + rsub) * DH;
    float di0 = 1.f, di1 = 1.f;
    if (SCALE) { di0 = dinv[r0 + rsub]; di1 = dinv[r0 + 16 + rsub]; }

#pragma unroll 1
    for (int np = 0; np < 4; np++) {
        uint2 ev0, ev1, ov0, ov1;
#pragma unroll
        for (int h = 0; h < 2; h++) {
            const int nt = np * 2 + h;
            f32x4 ah0 = (f32x4){0.f, 0.f, 0.f, 0.f};
            f32x4 ah1 = (f32x4){0.f, 0.f, 0.f, 0.f};
            const bf16_t* shb = wbase + (size_t)nt * KS * 512;
#pragma unroll
            for (int ks = 0; ks < KS; ks++) {
                bf16x8 wh = *(const bf16x8*)(shb + ks * 512);
                ah0 = __builtin_amdgcn_mfma_f32_16x16x32_bf16(wh, a[0][ks], ah0, 0, 0, 0);
                ah1 = __builtin_amdgcn_mfma_f32_16x16x32_bf16(wh, a[1][ks], ah1, 0, 0, 0);
            }
            const float4 bb = *(const float4*)(bias + nh * 128 + nt * 16 + cq);
            float v00 = fmaxf(ah0[0] + bb.x, 0.f), v01 = fmaxf(ah0[1] + bb.y, 0.f);
            float v02 = fmaxf(ah0[2] + bb.z, 0.f), v03 = fmaxf(ah0[3] + bb.w, 0.f);
            float v10 = fmaxf(ah1[0] + bb.x, 0.f), v11 = fmaxf(ah1[1] + bb.y, 0.f);
            float v12 = fmaxf(ah1[2] + bb.z, 0.f), v13 = fmaxf(ah1[3] + bb.w, 0.f);
            if (SCALE) {
                v00 *= di0; v01 *= di0; v02 *= di0; v03 *= di0;
                v10 *= di1; v11 *= di1; v12 *= di1; v13 *= di1;
            }
            uint2 p0, p1;
            p0.x = (unsigned)f2bf(v00) | ((unsigned)f2bf(v01) << 16);
            p0.y = (unsigned)f2bf(v02) | ((unsigned)f2bf(v03) << 16);
            p1.x = (unsigned)f2bf(v10) | ((unsigned)f2bf(v11) << 16);
            p1.y = (unsigned)f2bf(v12) | ((unsigned)f2bf(v13) << 16);
            if (h == 0) { ev0 = p0; ev1 = p1; }
            else        { ov0 = p0; ov1 = p1; }
        }
        // cross-lane exchange with partner (lane^16)
        uint2 s0 = lowhalf ? ov0 : ev0;
        uint2 s1 = lowhalf ? ov1 : ev1;
        uint2 rx0, rx1;
        rx0.x = (unsigned)__shfl_xor((int)s0.x, 16, 64);
        rx0.y = (unsigned)__shfl_xor((int)s0.y, 16, 64);
        rx1.x = (unsigned)__shfl_xor((int)s1.x, 16, 64);
        rx1.y = (unsigned)__shfl_xor((int)s1.y, 16, 64);
        const int colbase = nh * 128 + np * 32 + (lowhalf ? cq : (16 + cq - 4));
        uint4 w0, w1;
        if (lowhalf) {
            w0 = make_uint4(ev0.x, ev0.y, rx0.x, rx0.y);
            w1 = make_uint4(ev1.x, ev1.y, rx1.x, rx1.y);
        } else {
            w0 = make_uint4(rx0.x, rx0.y, ov0.x, ov0.y);
            w1 = make_uint4(rx1.x, rx1.y, ov1.x, ov1.y);
        }
        *(uint4*)(C + row0 + colbase) = w0;
        *(uint4*)(C + row1 + colbase) = w1;
    }
}

// --------------------------------------------------- fused pooling + classifier
// one 1024-thread block per graph: pool phase -> LDS gf[512] -> classifier.

__global__ __launch_bounds__(1024) void k_poolcls(
    const bf16_t* __restrict__ h, const int* __restrict__ gstart,
    const float* __restrict__ cw0, const float* __restrict__ cb0,
    const float* __restrict__ cw1, const float* __restrict__ cb1,
    float* __restrict__ out)
{
    __shared__ float ssum[32][DH];
    __shared__ float smax[32][DH];
    __shared__ float gf[512];
    __shared__ float red[2][4];
    int g = blockIdx.x;
    int t = threadIdx.x;
    int c = t & 31;                 // 8-dim chunk
    int r = t >> 5;                 // row group
    int s = gstart[g], e = gstart[g + 1];
    float sum[8], mx[8];
#pragma unroll
    for (int j = 0; j < 8; j++) { sum[j] = 0.f; mx[j] = 0.f; }  // h>=0 post-ReLU
    for (int i = s + r; i < e; i += 32) {
        uint4 v = *(const uint4*)(h + (size_t)i * DH + c * 8);
        float f[8]; unpack8(v, f);
#pragma unroll
        for (int j = 0; j < 8; j++) { sum[j] += f[j]; mx[j] = fmaxf(mx[j], f[j]); }
    }
#pragma unroll
    for (int j = 0; j < 8; j++) { ssum[r][c * 8 + j] = sum[j]; smax[r][c * 8 + j] = mx[j]; }
    __syncthreads();
#pragma unroll
    for (int off = 16; off > 0; off >>= 1) {
        if (r < off) {
#pragma unroll
            for (int j = 0; j < 8; j++) {
                int d = c * 8 + j;
                ssum[r][d] += ssum[r + off][d];
                smax[r][d] = fmaxf(smax[r][d], smax[r + off][d]);
            }
        }
        __syncthreads();
    }
    if (r == 0) {
        float inv = 1.0f / fmaxf((float)(e - s), 1.0f);
#pragma unroll
        for (int j = 0; j < 8; j++) {
            int d = c * 8 + j;
            gf[d]       = ssum[0][d] * inv;
            gf[256 + d] = smax[0][d];
        }
    }
    __syncthreads();
    // classifier: threads 0..255
    if (t < 256) {
        float acc = cb0[t];
#pragma unroll 8
        for (int k = 0; k < 512; ++k)
            acc = fmaf(gf[k], cw0[(size_t)k * DH + t], acc);
        float hc = fmaxf(acc, 0.f);
        float p0 = hc * cw1[t * 2 + 0];
        float p1 = hc * cw1[t * 2 + 1];
        for (int off = 32; off > 0; off >>= 1) {
            p0 += __shfl_down(p0, off, 64);
            p1 += __shfl_down(p1, off, 64);
        }
        int wv = t >> 6;
        if ((t & 63) == 0) { red[0][wv] = p0; red[1][wv] = p1; }
    }
    __syncthreads();
    if (t == 0) {
        float s0 = cb1[0], s1 = cb1[1];
#pragma unroll
        for (int w = 0; w < 4; w++) { s0 += red[0][w]; s1 += red[1][w]; }
        out[g * 2 + 0] = s0;
        out[g * 2 + 1] = s1;
    }
}

// ------------------------------------------------------------------ launch

extern "C" void kernel_launch(void* const* d_in, const int* in_sizes, int n_in,
                              void* d_out, int out_size, void* d_ws, size_t ws_size,
                              hipStream_t stream)
{
    const int*   node_ids = (const int*)d_in[0];
    const int*   edge_src = (const int*)d_in[1];      // edge_index[0]
    const int*   edge_dst = edge_src + NE;            // edge_index[1]
    const int*   batch    = (const int*)d_in[2];
    const float* emb = (const float*)d_in[3];
    const float* w0  = (const float*)d_in[4];
    const float* b0  = (const float*)d_in[5];
    const float* w1  = (const float*)d_in[6];
    const float* b1  = (const float*)d_in[7];
    const float* w2  = (const float*)d_in[8];
    const float* b2  = (const float*)d_in[9];
    const float* w3  = (const float*)d_in[10];
    const float* b3  = (const float*)d_in[11];
    const float* cw0 = (const float*)d_in[12];
    const float* cb0 = (const float*)d_in[13];
    const float* cw1 = (const float*)d_in[14];
    const float* cb1 = (const float*)d_in[15];
    float* out = (float*)d_out;

    char* p = (char*)d_ws;
    auto alloc = [&](size_t b) -> void* {
        void* r = (void*)p;
        p += (b + 255) & ~(size_t)255;
        return r;
    };
    float*  dinv   = (float*)alloc((size_t)NPAD * 4);
    int*    rowptr = (int*)alloc((size_t)(NN + 1) * 4);
    int*    cnt    = (int*)alloc((size_t)NN * 4);
    int*    col    = (int*)alloc((size_t)NE * 4);
    int*    bsum   = (int*)alloc(256 * 4);
    int*    gstart = (int*)alloc((NG + 1) * 4);
    // frag-packed bf16 weights: layer0 KS=4, layers1-3 KS=8
    bf16_t* whi0 = (bf16_t*)alloc((size_t)16 * 4 * 512 * 2);
    bf16_t* whiL[3];
    for (int l = 0; l < 3; l++)
        whiL[l] = (bf16_t*)alloc((size_t)16 * 8 * 512 * 2);
    bf16_t* hA = (bf16_t*)alloc((size_t)NPAD * DH * 2);   // 76.8 MB
    bf16_t* hB = (bf16_t*)alloc((size_t)NPAD * DH * 2);   // 76.8 MB
    (void)ws_size; (void)in_sizes; (void)n_in; (void)out_size;

    // weight fragment prep: all 4 layers, one launch (hi only)
    k_wprep4<<<dim3(32, 4), 256, 0, stream>>>(w0, w1, w2, w3,
        whi0, whiL[0], whiL[1], whiL[2]);

    // degree + CSR (dst-sorted) + graph offsets
    k_zero<<<(NN + 255) / 256, 256, 0, stream>>>(cnt, NN);
    k_hist<<<(NE + 255) / 256, 256, 0, stream>>>(edge_dst, cnt);
    const int NB = (NN + SCAN_CHUNK - 1) / SCAN_CHUNK;   // 147
    k_scan1<<<NB, 256, 0, stream>>>(cnt, bsum, dinv);    // also computes dinv
    k_scan2<<<1, 256, 0, stream>>>(bsum, NB);            // parallel exclusive scan
    k_scan3<<<NB, 256, 0, stream>>>(cnt, bsum, rowptr);  // zeroes cnt for scatter
    k_scatter<<<(NE + 255) / 256, 256, 0, stream>>>(edge_src, edge_dst, rowptr,
                                                    cnt, col, batch, gstart);

    // layer 0: fused embed+aggregate (emb fp32 gather, L2-resident) -> hB
    k_agg_emb<<<(NN * 8 + 255) / 256, 256, 0, stream>>>(node_ids, emb, dinv, rowptr, col, hB);
    k_gemm_mfma<4, true><<<(NPAD / 256) * 2, 512, 0, stream>>>(hB, whi0, b0, dinv, hA);

    // layers 1..2: aggregate then transform (store z_l); layer 3 stores h
    k_agg<256><<<(NN * 16 + 255) / 256, 256, 0, stream>>>(hA, dinv, rowptr, col, hB);
    k_gemm_mfma<8, true><<<(NPAD / 256) * 2, 512, 0, stream>>>(hB, whiL[0], b1, dinv, hA);
    k_agg<256><<<(NN * 16 + 255) / 256, 256, 0, stream>>>(hA, dinv, rowptr, col, hB);
    k_gemm_mfma<8, true><<<(NPAD / 256) * 2, 512, 0, stream>>>(hB, whiL[1], b2, dinv, hA);
    k_agg<256><<<(NN * 16 + 255) / 256, 256, 0, stream>>>(hA, dinv, rowptr, col, hB);
    k_gemm_mfma<8, false><<<(NPAD / 256) * 2, 512, 0, stream>>>(hB, whiL[2], b3, dinv, hA);

    // fused pooling + classifier
    k_poolcls<<<NG, 1024, 0, stream>>>(hA, gstart, cw0, cb0, cw1, cb1, out);
}

// Round 26
// 398.804 us; speedup vs baseline: 1.1241x; 1.1241x over previous
//
#include <hip/hip_runtime.h>
#include <stdint.h>
#include <stddef.h>

#define NN 150000   // nodes
#define NPAD 150016 // padded rows (= 586 * 256)
#define NE 300000   // edges
#define NG 256      // graphs
#define DE 128      // embedding dim
#define DH 256      // hidden dim

typedef unsigned short bf16_t;
typedef __attribute__((ext_vector_type(8))) short bf16x8;
typedef __attribute__((ext_vector_type(4))) float f32x4;

__device__ __forceinline__ float bf2f(unsigned int u) {
    union { unsigned int i; float f; } v; v.i = u << 16; return v.f;
}
__device__ __forceinline__ bf16_t f2bf(float f) {
    union { float f; unsigned int i; } v; v.f = f;
    unsigned int x = v.i;
    return (bf16_t)((x + 0x7fffu + ((x >> 16) & 1u)) >> 16);   // RNE
}

// ---------------------------------------------------------------- utility

__global__ void k_zero(int* __restrict__ p, int n) {
    int i = blockIdx.x * blockDim.x + threadIdx.x;
    if (i < n) p[i] = 0;
}

// ---------------------------------------------------------------- precompute

__global__ void k_hist(const int* __restrict__ dst, int* __restrict__ cnt) {
    int e = blockIdx.x * blockDim.x + threadIdx.x;
    if (e < NE) atomicAdd(&cnt[dst[e]], 1);
}

#define SCAN_CHUNK 1024
// block sums for rowptr scan; ALSO computes dinv (padded: [NN,NPAD) -> 0)
__global__ void k_scan1(const int* __restrict__ cnt, int* __restrict__ bsum,
                        float* __restrict__ dinv) {
    __shared__ int sd[256];
    int base = blockIdx.x * SCAN_CHUNK;
    int t = threadIdx.x;
    int s = 0;
#pragma unroll
    for (int j = 0; j < 4; j++) {
        int i = base + t * 4 + j;
        if (i < NN) s += cnt[i];
        if (i < NPAD) dinv[i] = (i < NN) ? rsqrtf((float)(cnt[i] + 1)) : 0.f;
    }
    sd[t] = s; __syncthreads();
    for (int off = 128; off > 0; off >>= 1) {
        if (t < off) sd[t] += sd[t + off];
        __syncthreads();
    }
    if (t == 0) bsum[blockIdx.x] = sd[0];
}

// parallel exclusive scan over block sums (nb <= 256)
__global__ void k_scan2(int* __restrict__ bsum, int nb) {
    __shared__ int sd[256];
    int t = threadIdx.x;
    int v = (t < nb) ? bsum[t] : 0;
    sd[t] = v; __syncthreads();
    for (int off = 1; off < 256; off <<= 1) {
        int x = (t >= off) ? sd[t - off] : 0;
        __syncthreads();
        sd[t] += x;
        __syncthreads();
    }
    if (t < nb) bsum[t] = sd[t] - v;   // exclusive prefix
}

// also zeroes cnt after reading (fill-cursor prep for k_scatter)
__global__ void k_scan3(int* __restrict__ cnt, const int* __restrict__ bsum,
                        int* __restrict__ rowptr) {
    __shared__ int sd[256];
    int base = blockIdx.x * SCAN_CHUNK;
    int t = threadIdx.x;
    int v[4]; int s = 0;
#pragma unroll
    for (int j = 0; j < 4; j++) {
        int i = base + t * 4 + j;
        v[j] = (i < NN) ? cnt[i] : 0;
        s += v[j];
    }
    sd[t] = s; __syncthreads();
    for (int off = 1; off < 256; off <<= 1) {
        int x = (t >= off) ? sd[t - off] : 0;
        __syncthreads();
        sd[t] += x;
        __syncthreads();
    }
    int pre = bsum[blockIdx.x] + ((t == 0) ? 0 : sd[t - 1]);
#pragma unroll
    for (int j = 0; j < 4; j++) {
        int i = base + t * 4 + j;
        if (i < NN) { rowptr[i] = pre; pre += v[j]; cnt[i] = 0; }
    }
    if (blockIdx.x == 0 && t == 0) rowptr[NN] = NE;
}

// CSR scatter; ALSO computes gstart (independent work, same grid covers NN)
__global__ void k_scatter(const int* __restrict__ src, const int* __restrict__ dst,
                          const int* __restrict__ rowptr, int* __restrict__ fill,
                          int* __restrict__ col, const int* __restrict__ batch,
                          int* __restrict__ gstart) {
    int e = blockIdx.x * blockDim.x + threadIdx.x;
    if (e < NE) {
        int d = dst[e];
        int p = rowptr[d] + atomicAdd(&fill[d], 1);
        col[p] = src[e];
    }
    if (e < NN) {
        int g = batch[e];
        int gp = (e == 0) ? -1 : batch[e - 1];
        for (int gg = gp + 1; gg <= g; ++gg) gstart[gg] = e;
        if (e == NN - 1) {
            for (int gg = g + 1; gg <= NG; ++gg) gstart[gg] = NN;
        }
    }
}

// ------------------------------------------------------- weight fragment prep
// all 4 layers in one launch; layer = blockIdx.y, KS = layer? 8 : 4.
// element (q,l,j) = W[ks*32 + (l>>4)*8 + j][nt*16 + (l&15)], q = nt*KS+ks

__global__ void k_wprep4(const float* __restrict__ W0, const float* __restrict__ W1,
                         const float* __restrict__ W2, const float* __restrict__ W3,
                         bf16_t* __restrict__ h0, bf16_t* __restrict__ h1,
                         bf16_t* __restrict__ h2, bf16_t* __restrict__ h3) {
    int layer = blockIdx.y;
    int KS = (layer == 0) ? 4 : 8;
    const float* W = (layer == 0) ? W0 : (layer == 1) ? W1 : (layer == 2) ? W2 : W3;
    bf16_t* whi = (layer == 0) ? h0 : (layer == 1) ? h1 : (layer == 2) ? h2 : h3;
    int tid = blockIdx.x * blockDim.x + threadIdx.x;
    int total = 16 * KS * 64;
    if (tid >= total) return;
    int l = tid & 63, q = tid >> 6;
    int ks = q % KS;
    int nt = q / KS;
    int row0 = ks * 32 + (l >> 4) * 8;
    int colc = nt * 16 + (l & 15);
    unsigned hi[8];
#pragma unroll
    for (int j = 0; j < 8; j++)
        hi[j] = f2bf(W[(size_t)(row0 + j) * DH + colc]);
    uint4 ph;
    ph.x = hi[0] | (hi[1] << 16); ph.y = hi[2] | (hi[3] << 16);
    ph.z = hi[4] | (hi[5] << 16); ph.w = hi[6] | (hi[7] << 16);
    ((uint4*)whi)[q * 64 + l] = ph;
}

__device__ __forceinline__ void unpack8(uint4 u, float* f) {
    f[0] = bf2f(u.x & 0xffffu); f[1] = bf2f(u.x >> 16);
    f[2] = bf2f(u.y & 0xffffu); f[3] = bf2f(u.y >> 16);
    f[4] = bf2f(u.z & 0xffffu); f[5] = bf2f(u.z >> 16);
    f[6] = bf2f(u.w & 0xffffu); f[7] = bf2f(u.w >> 16);
}
__device__ __forceinline__ uint4 pack8(const float* f, float sc) {
    uint4 o;
    o.x = (unsigned)f2bf(sc * f[0]) | ((unsigned)f2bf(sc * f[1]) << 16);
    o.y = (unsigned)f2bf(sc * f[2]) | ((unsigned)f2bf(sc * f[3]) << 16);
    o.z = (unsigned)f2bf(sc * f[4]) | ((unsigned)f2bf(sc * f[5]) << 16);
    o.w = (unsigned)f2bf(sc * f[6]) | ((unsigned)f2bf(sc * f[7]) << 16);
    return o;
}

// ------------------------------------------- fused embed + layer-0 aggregation
// y[i] = dinv[i]*( dinv[i]*emb[nids[i]] + sum_nb dinv[s]*emb[nids[s]] ), bf16.
// thread = (node, 16-elem chunk): 8 threads/node, 32B per gather step.

__global__ void k_agg_emb(const int* __restrict__ nids, const float* __restrict__ emb,
                          const float* __restrict__ dinv, const int* __restrict__ rowptr,
                          const int* __restrict__ col, bf16_t* __restrict__ y) {
    int idx = blockIdx.x * 256 + threadIdx.x;
    if (idx >= NN * 8) return;
    int node = idx >> 3;
    int c = idx & 7;
    size_t off = (size_t)c * 16;
    float di = dinv[node];
    float acc[16];
    {
        const float4* sp = (const float4*)(emb + (size_t)nids[node] * DE + off);
        float4 u0 = sp[0], u1 = sp[1], u2 = sp[2], u3 = sp[3];
        acc[0] = di * u0.x;  acc[1] = di * u0.y;  acc[2] = di * u0.z;  acc[3] = di * u0.w;
        acc[4] = di * u1.x;  acc[5] = di * u1.y;  acc[6] = di * u1.z;  acc[7] = di * u1.w;
        acc[8] = di * u2.x;  acc[9] = di * u2.y;  acc[10] = di * u2.z; acc[11] = di * u2.w;
        acc[12] = di * u3.x; acc[13] = di * u3.y; acc[14] = di * u3.z; acc[15] = di * u3.w;
    }
    int r0 = rowptr[node], r1 = rowptr[node + 1];
    for (int r = r0; r < r1; ++r) {
        int s = col[r];
        float ds = dinv[s];
        const float4* np = (const float4*)(emb + (size_t)nids[s] * DE + off);
        float4 n0 = np[0], n1 = np[1], n2 = np[2], n3 = np[3];
        acc[0] = fmaf(ds, n0.x, acc[0]);   acc[1] = fmaf(ds, n0.y, acc[1]);
        acc[2] = fmaf(ds, n0.z, acc[2]);   acc[3] = fmaf(ds, n0.w, acc[3]);
        acc[4] = fmaf(ds, n1.x, acc[4]);   acc[5] = fmaf(ds, n1.y, acc[5]);
        acc[6] = fmaf(ds, n1.z, acc[6]);   acc[7] = fmaf(ds, n1.w, acc[7]);
        acc[8] = fmaf(ds, n2.x, acc[8]);   acc[9] = fmaf(ds, n2.y, acc[9]);
        acc[10] = fmaf(ds, n2.z, acc[10]); acc[11] = fmaf(ds, n2.w, acc[11]);
        acc[12] = fmaf(ds, n3.x, acc[12]); acc[13] = fmaf(ds, n3.y, acc[13]);
        acc[14] = fmaf(ds, n3.z, acc[14]); acc[15] = fmaf(ds, n3.w, acc[15]);
    }
    uint4* yp = (uint4*)(y + (size_t)node * DE + off);
    yp[0] = pack8(acc, di);
    yp[1] = pack8(acc + 8, di);
}

// ------------------------------------------------------------- aggregation
// x holds z = dinv*h (pre-scaled). y[i] = dinv[i] * ( z[i] + sum_nb z[s] ).
// thread = (node, 16-elem chunk): two independent uint4 gathers per neighbor.

template <int W>
__global__ void k_agg(const bf16_t* __restrict__ x, const float* __restrict__ dinv,
                      const int* __restrict__ rowptr, const int* __restrict__ col,
                      bf16_t* __restrict__ y) {
    constexpr int CH = W / 16;                 // chunks per node
    constexpr int SH = (W == 128) ? 3 : 4;
    int idx = blockIdx.x * 256 + threadIdx.x;
    if (idx >= NN * CH) return;
    int node = idx >> SH;
    int c = idx & (CH - 1);
    size_t off = (size_t)c * 16;
    float di = dinv[node];
    float acc[16];
    {
        const uint4* xp = (const uint4*)(x + (size_t)node * W + off);
        uint4 u0 = xp[0], u1 = xp[1];
        unpack8(u0, acc);
        unpack8(u1, acc + 8);
    }
    int r0 = rowptr[node], r1 = rowptr[node + 1];
    for (int r = r0; r < r1; ++r) {
        int s = col[r];
        const uint4* np = (const uint4*)(x + (size_t)s * W + off);
        uint4 v0 = np[0], v1 = np[1];
        float f[16];
        unpack8(v0, f);
        unpack8(v1, f + 8);
#pragma unroll
        for (int j = 0; j < 16; j++) acc[j] += f[j];
    }
    uint4* yp = (uint4*)(y + (size_t)node * W + off);
    yp[0] = pack8(acc, di);
    yp[1] = pack8(acc + 8, di);
}

// ------------------------------------------------------------------- GEMM
// C[NPAD x 256] = relu(A[NPAD x K] @ W[K x 256] + bias)  [then *dinv if SCALE]
// Round-24 measured best (48.7 us): full W_hi half in 64KB LDS (round 25
// proved occupancy is NOT LDS-bound -- LDS=0 kept occ at 32% and lost 14 us
// of LDS-vs-L1 latency). Swapped-operand MFMA + paired-nt sector stores
// (WRITE 112->88 MB). 1-D grid, nh = blockIdx.x & 1 (adjacent halves share
// the A tile in L2). One barrier per block; direct uint4 stores.

template <int KS, bool SCALE>
__global__ __launch_bounds__(512, 4) void k_gemm_mfma(
    const bf16_t* __restrict__ A, const bf16_t* __restrict__ whi,
    const float* __restrict__ bias, const float* __restrict__ dinv,
    bf16_t* __restrict__ C)
{
    constexpr int K = KS * 32;
    __shared__ bf16_t sW[8 * KS * 512];           // 64 KB (KS=8) / 32 KB (KS=4)
    const int t = threadIdx.x;
    const int lane = t & 63;
    const int wave = t >> 6;                      // 0..7
    const int nh = blockIdx.x & 1;
    const int br0 = (blockIdx.x >> 1) * 256;

    // stage W_hi for this nh (nt = nh*8 .. nh*8+7) into LDS, linear copy
    {
        const uint4* gsrc = (const uint4*)whi + ((size_t)nh * 8) * KS * 64;
        uint4* sdst = (uint4*)sW;
#pragma unroll
        for (int i = 0; i < (8 * KS * 64) / 512; i++)
            sdst[t + i * 512] = gsrc[t + i * 512];
    }

    // A fragments: wave's 32 rows (2 subtiles of 16), full K.
    const int r0 = br0 + wave * 32;
    bf16x8 a[2][KS];
#pragma unroll
    for (int s = 0; s < 2; s++) {
        const bf16_t* ap = A + (size_t)(r0 + s * 16 + (lane & 15)) * K + (lane >> 4) * 8;
#pragma unroll
        for (int ks = 0; ks < KS; ks++)
            a[s][ks] = *(const bf16x8*)(ap + ks * 32);
    }
    __syncthreads();

    const int rsub = lane & 15;                   // output row within subtile
    const int cq = (lane >> 4) * 4;               // col base within nt tile
    const bool lowhalf = ((lane >> 4) & 1) == 0;  // partner = lane ^ 16
    const size_t row0 = (size_t)(r0 + rsub) * DH;
    const size_t row1 = (size_t)(r0 + 16 + rsub) * DH;
    float di0 = 1.f, di1 = 1.f;
    if (SCALE) { di0 = dinv[r0 + rsub]; di1 = dinv[r0 + 16 + rsub]; }

#pragma unroll 1
    for (int np = 0; np < 4; np++) {
        uint2 ev0, ev1, ov0, ov1;
#pragma unroll
        for (int h = 0; h < 2; h++) {
            const int nt = np * 2 + h;
            f32x4 ah0 = (f32x4){0.f, 0.f, 0.f, 0.f};
            f32x4 ah1 = (f32x4){0.f, 0.f, 0.f, 0.f};
            const bf16_t* shb = sW + (size_t)nt * KS * 512 + lane * 8;
#pragma unroll
            for (int ks = 0; ks < KS; ks++) {
                bf16x8 wh = *(const bf16x8*)(shb + ks * 512);
                ah0 = __builtin_amdgcn_mfma_f32_16x16x32_bf16(wh, a[0][ks], ah0, 0, 0, 0);
                ah1 = __builtin_amdgcn_mfma_f32_16x16x32_bf16(wh, a[1][ks], ah1, 0, 0, 0);
            }
            const float4 bb = *(const float4*)(bias + nh * 128 + nt * 16 + cq);
            float v00 = fmaxf(ah0[0] + bb.x, 0.f), v01 = fmaxf(ah0[1] + bb.y, 0.f);
            float v02 = fmaxf(ah0[2] + bb.z, 0.f), v03 = fmaxf(ah0[3] + bb.w, 0.f);
            float v10 = fmaxf(ah1[0] + bb.x, 0.f), v11 = fmaxf(ah1[1] + bb.y, 0.f);
            float v12 = fmaxf(ah1[2] + bb.z, 0.f), v13 = fmaxf(ah1[3] + bb.w, 0.f);
            if (SCALE) {
                v00 *= di0; v01 *= di0; v02 *= di0; v03 *= di0;
                v10 *= di1; v11 *= di1; v12 *= di1; v13 *= di1;
            }
            uint2 p0, p1;
            p0.x = (unsigned)f2bf(v00) | ((unsigned)f2bf(v01) << 16);
            p0.y = (unsigned)f2bf(v02) | ((unsigned)f2bf(v03) << 16);
            p1.x = (unsigned)f2bf(v10) | ((unsigned)f2bf(v11) << 16);
            p1.y = (unsigned)f2bf(v12) | ((unsigned)f2bf(v13) << 16);
            if (h == 0) { ev0 = p0; ev1 = p1; }
            else        { ov0 = p0; ov1 = p1; }
        }
        // cross-lane exchange with partner (lane^16)
        uint2 s0 = lowhalf ? ov0 : ev0;
        uint2 s1 = lowhalf ? ov1 : ev1;
        uint2 rx0, rx1;
        rx0.x = (unsigned)__shfl_xor((int)s0.x, 16, 64);
        rx0.y = (unsigned)__shfl_xor((int)s0.y, 16, 64);
        rx1.x = (unsigned)__shfl_xor((int)s1.x, 16, 64);
        rx1.y = (unsigned)__shfl_xor((int)s1.y, 16, 64);
        const int colbase = nh * 128 + np * 32 + (lowhalf ? cq : (16 + cq - 4));
        uint4 w0, w1;
        if (lowhalf) {
            w0 = make_uint4(ev0.x, ev0.y, rx0.x, rx0.y);
            w1 = make_uint4(ev1.x, ev1.y, rx1.x, rx1.y);
        } else {
            w0 = make_uint4(rx0.x, rx0.y, ov0.x, ov0.y);
            w1 = make_uint4(rx1.x, rx1.y, ov1.x, ov1.y);
        }
        *(uint4*)(C + row0 + colbase) = w0;
        *(uint4*)(C + row1 + colbase) = w1;
    }
}

// --------------------------------------------------- fused pooling + classifier
// one 1024-thread block per graph: pool phase -> LDS gf[512] -> classifier.

__global__ __launch_bounds__(1024) void k_poolcls(
    const bf16_t* __restrict__ h, const int* __restrict__ gstart,
    const float* __restrict__ cw0, const float* __restrict__ cb0,
    const float* __restrict__ cw1, const float* __restrict__ cb1,
    float* __restrict__ out)
{
    __shared__ float ssum[32][DH];
    __shared__ float smax[32][DH];
    __shared__ float gf[512];
    __shared__ float red[2][4];
    int g = blockIdx.x;
    int t = threadIdx.x;
    int c = t & 31;                 // 8-dim chunk
    int r = t >> 5;                 // row group
    int s = gstart[g], e = gstart[g + 1];
    float sum[8], mx[8];
#pragma unroll
    for (int j = 0; j < 8; j++) { sum[j] = 0.f; mx[j] = 0.f; }  // h>=0 post-ReLU
    for (int i = s + r; i < e; i += 32) {
        uint4 v = *(const uint4*)(h + (size_t)i * DH + c * 8);
        float f[8]; unpack8(v, f);
#pragma unroll
        for (int j = 0; j < 8; j++) { sum[j] += f[j]; mx[j] = fmaxf(mx[j], f[j]); }
    }
#pragma unroll
    for (int j = 0; j < 8; j++) { ssum[r][c * 8 + j] = sum[j]; smax[r][c * 8 + j] = mx[j]; }
    __syncthreads();
#pragma unroll
    for (int off = 16; off > 0; off >>= 1) {
        if (r < off) {
#pragma unroll
            for (int j = 0; j < 8; j++) {
                int d = c * 8 + j;
                ssum[r][d] += ssum[r + off][d];
                smax[r][d] = fmaxf(smax[r][d], smax[r + off][d]);
            }
        }
        __syncthreads();
    }
    if (r == 0) {
        float inv = 1.0f / fmaxf((float)(e - s), 1.0f);
#pragma unroll
        for (int j = 0; j < 8; j++) {
            int d = c * 8 + j;
            gf[d]       = ssum[0][d] * inv;
            gf[256 + d] = smax[0][d];
        }
    }
    __syncthreads();
    // classifier: threads 0..255
    if (t < 256) {
        float acc = cb0[t];
#pragma unroll 8
        for (int k = 0; k < 512; ++k)
            acc = fmaf(gf[k], cw0[(size_t)k * DH + t], acc);
        float hc = fmaxf(acc, 0.f);
        float p0 = hc * cw1[t * 2 + 0];
        float p1 = hc * cw1[t * 2 + 1];
        for (int off = 32; off > 0; off >>= 1) {
            p0 += __shfl_down(p0, off, 64);
            p1 += __shfl_down(p1, off, 64);
        }
        int wv = t >> 6;
        if ((t & 63) == 0) { red[0][wv] = p0; red[1][wv] = p1; }
    }
    __syncthreads();
    if (t == 0) {
        float s0 = cb1[0], s1 = cb1[1];
#pragma unroll
        for (int w = 0; w < 4; w++) { s0 += red[0][w]; s1 += red[1][w]; }
        out[g * 2 + 0] = s0;
        out[g * 2 + 1] = s1;
    }
}

// ------------------------------------------------------------------ launch

extern "C" void kernel_launch(void* const* d_in, const int* in_sizes, int n_in,
                              void* d_out, int out_size, void* d_ws, size_t ws_size,
                              hipStream_t stream)
{
    const int*   node_ids = (const int*)d_in[0];
    const int*   edge_src = (const int*)d_in[1];      // edge_index[0]
    const int*   edge_dst = edge_src + NE;            // edge_index[1]
    const int*   batch    = (const int*)d_in[2];
    const float* emb = (const float*)d_in[3];
    const float* w0  = (const float*)d_in[4];
    const float* b0  = (const float*)d_in[5];
    const float* w1  = (const float*)d_in[6];
    const float* b1  = (const float*)d_in[7];
    const float* w2  = (const float*)d_in[8];
    const float* b2  = (const float*)d_in[9];
    const float* w3  = (const float*)d_in[10];
    const float* b3  = (const float*)d_in[11];
    const float* cw0 = (const float*)d_in[12];
    const float* cb0 = (const float*)d_in[13];
    const float* cw1 = (const float*)d_in[14];
    const float* cb1 = (const float*)d_in[15];
    float* out = (float*)d_out;

    char* p = (char*)d_ws;
    auto alloc = [&](size_t b) -> void* {
        void* r = (void*)p;
        p += (b + 255) & ~(size_t)255;
        return r;
    };
    float*  dinv   = (float*)alloc((size_t)NPAD * 4);
    int*    rowptr = (int*)alloc((size_t)(NN + 1) * 4);
    int*    cnt    = (int*)alloc((size_t)NN * 4);
    int*    col    = (int*)alloc((size_t)NE * 4);
    int*    bsum   = (int*)alloc(256 * 4);
    int*    gstart = (int*)alloc((NG + 1) * 4);
    // frag-packed bf16 weights: layer0 KS=4, layers1-3 KS=8
    bf16_t* whi0 = (bf16_t*)alloc((size_t)16 * 4 * 512 * 2);
    bf16_t* whiL[3];
    for (int l = 0; l < 3; l++)
        whiL[l] = (bf16_t*)alloc((size_t)16 * 8 * 512 * 2);
    bf16_t* hA = (bf16_t*)alloc((size_t)NPAD * DH * 2);   // 76.8 MB
    bf16_t* hB = (bf16_t*)alloc((size_t)NPAD * DH * 2);   // 76.8 MB
    (void)ws_size; (void)in_sizes; (void)n_in; (void)out_size;

    // weight fragment prep: all 4 layers, one launch (hi only)
    k_wprep4<<<dim3(32, 4), 256, 0, stream>>>(w0, w1, w2, w3,
        whi0, whiL[0], whiL[1], whiL[2]);

    // degree + CSR (dst-sorted) + graph offsets
    k_zero<<<(NN + 255) / 256, 256, 0, stream>>>(cnt, NN);
    k_hist<<<(NE + 255) / 256, 256, 0, stream>>>(edge_dst, cnt);
    const int NB = (NN + SCAN_CHUNK - 1) / SCAN_CHUNK;   // 147
    k_scan1<<<NB, 256, 0, stream>>>(cnt, bsum, dinv);    // also computes dinv
    k_scan2<<<1, 256, 0, stream>>>(bsum, NB);            // parallel exclusive scan
    k_scan3<<<NB, 256, 0, stream>>>(cnt, bsum, rowptr);  // zeroes cnt for scatter
    k_scatter<<<(NE + 255) / 256, 256, 0, stream>>>(edge_src, edge_dst, rowptr,
                                                    cnt, col, batch, gstart);

    // layer 0: fused embed+aggregate (emb fp32 gather, L2-resident) -> hB
    k_agg_emb<<<(NN * 8 + 255) / 256, 256, 0, stream>>>(node_ids, emb, dinv, rowptr, col, hB);
    k_gemm_mfma<4, true><<<(NPAD / 256) * 2, 512, 0, stream>>>(hB, whi0, b0, dinv, hA);

    // layers 1..2: aggregate then transform (store z_l); layer 3 stores h
    k_agg<256><<<(NN * 16 + 255) / 256, 256, 0, stream>>>(hA, dinv, rowptr, col, hB);
    k_gemm_mfma<8, true><<<(NPAD / 256) * 2, 512, 0, stream>>>(hB, whiL[0], b1, dinv, hA);
    k_agg<256><<<(NN * 16 + 255) / 256, 256, 0, stream>>>(hA, dinv, rowptr, col, hB);
    k_gemm_mfma<8, true><<<(NPAD / 256) * 2, 512, 0, stream>>>(hB, whiL[1], b2, dinv, hA);
    k_agg<256><<<(NN * 16 + 255) / 256, 256, 0, stream>>>(hA, dinv, rowptr, col, hB);
    k_gemm_mfma<8, false><<<(NPAD / 256) * 2, 512, 0, stream>>>(hB, whiL[2], b3, dinv, hA);

    // fused pooling + classifier
    k_poolcls<<<NG, 1024, 0, stream>>>(hA, gstart, cw0, cb0, cw1, cb1, out);
}